// Round 5
// baseline (770.211 us; speedup 1.0000x reference)
//
#include <hip/hip_runtime.h>
#include <hip/hip_bf16.h>
#include <cstddef>

#define N_NODES 50000
#define N_EDGES 800000
#define HDIM    128
#define TME     64
#define TMN     64

// padded LDS row strides (bytes): break the 256B-stride bank aliasing
#define RB128   272     // 128 bf16 cols + 16B pad
#define RB256   528     // 256 bf16 cols + 16B pad

typedef __attribute__((ext_vector_type(4))) float f32x4;
typedef __attribute__((ext_vector_type(8))) short bf16x8;

// pack offsets (bf16 elements)
#define OFF_EW0T 0
#define OFF_EW0B 16384
#define OFF_EW1  32768
#define OFF_CW0  49152
#define OFF_NW0  65536
#define OFF_NW1  98304
#define PACK_ELEMS 114688

__device__ __forceinline__ float silu(float x) {
    float e = __expf(-x);
    return __fdividef(x, 1.0f + e);
}
__device__ __forceinline__ unsigned short f2bf(float f) {
    union { __hip_bfloat16 h; unsigned short u; } cv;
    cv.h = __float2bfloat16(f);
    return cv.u;
}
__device__ __forceinline__ unsigned int f2bf2(float a, float b) {
    union { __hip_bfloat162 h; unsigned int u; } cv;
    cv.h = __float22bfloat162_rn(float2{a, b});
    return cv.u;
}
__device__ __forceinline__ float bf2f(unsigned short u) {
    return __uint_as_float(((unsigned int)u) << 16);
}
__device__ __forceinline__ float bflo(unsigned int u) {   // low bf16 of a packed u32
    return __uint_as_float(u << 16);
}
__device__ __forceinline__ float bfhi(unsigned int u) {   // high bf16
    return __uint_as_float(u & 0xffff0000u);
}

// ---------------- weight pack ----------------
__global__ void pack_weights(const float* __restrict__ eW0, const float* __restrict__ eW1,
                             const float* __restrict__ cW0, const float* __restrict__ nW0,
                             const float* __restrict__ nW1, unsigned short* __restrict__ pack)
{
    int g = blockIdx.x * blockDim.x + threadIdx.x;   // 0 .. 14335
    int f = g >> 6;
    int lane = g & 63;
    const float* W; int base; int rowoff = 0;
    if (f < 32)       { W = eW0; base = OFF_EW0T; }
    else if (f < 64)  { W = eW0; base = OFF_EW0B; f -= 32; rowoff = 128; }
    else if (f < 96)  { W = eW1; base = OFF_EW1;  f -= 64; }
    else if (f < 128) { W = cW0; base = OFF_CW0;  f -= 96; }
    else if (f < 192) { W = nW0; base = OFF_NW0;  f -= 128; }
    else              { W = nW1; base = OFF_NW1;  f -= 192; }
    int KS = (base == OFF_NW0) ? 8 : 4;
    int cb = f / KS, ks = f % KS;
    int col = cb * 16 + (lane & 15);
    int kbase = rowoff + ks * 32 + ((lane >> 4) << 3);
#pragma unroll
    for (int j = 0; j < 8; ++j)
        pack[(size_t)base + ((size_t)(f * 64 + lane) * 8 + j)] =
            f2bf(W[(size_t)(kbase + j) * HDIM + col]);
}

// ---------------- counting-sort helpers ----------------
__global__ __launch_bounds__(1024)
void scan_kernel(const int* __restrict__ cnt, int* __restrict__ row_start,
                 int* __restrict__ cursor) {
    __shared__ int part[1024];
    const int t = threadIdx.x;
    const int PER = (N_NODES + 1023) / 1024;   // 49
    const int base = t * PER;
    int s = 0;
    for (int i = 0; i < PER; ++i) {
        int idx = base + i;
        if (idx < N_NODES) s += cnt[idx];
    }
    part[t] = s;
    __syncthreads();
    for (int off = 1; off < 1024; off <<= 1) {
        int tmp = (t >= off) ? part[t - off] : 0;
        __syncthreads();
        part[t] += tmp;
        __syncthreads();
    }
    int run = part[t] - s;    // exclusive prefix
    for (int i = 0; i < PER; ++i) {
        int idx = base + i;
        if (idx < N_NODES) {
            row_start[idx] = run;
            cursor[idx]    = run;
            run += cnt[idx];
        }
    }
    if (t == 1023) row_start[N_NODES] = part[1023];
}

__global__ void scatter_kernel(const int* __restrict__ eidx, int* __restrict__ cursor,
                               int* __restrict__ rows_s, int* __restrict__ cols_s) {
    int e = (blockIdx.x * blockDim.x + threadIdx.x) * 4;
    if (e + 3 < N_EDGES) {
        int4 r4 = *(const int4*)(eidx + e);
        int4 c4 = *(const int4*)(eidx + N_EDGES + e);
        int p;
        p = atomicAdd(&cursor[r4.x], 1); rows_s[p] = r4.x; cols_s[p] = c4.x;
        p = atomicAdd(&cursor[r4.y], 1); rows_s[p] = r4.y; cols_s[p] = c4.y;
        p = atomicAdd(&cursor[r4.z], 1); rows_s[p] = r4.z; cols_s[p] = c4.z;
        p = atomicAdd(&cursor[r4.w], 1); rows_s[p] = r4.w; cols_s[p] = c4.w;
    } else {
        for (int i = e; i < N_EDGES; ++i) {
            int r = eidx[i], c = eidx[N_EDGES + i];
            int p = atomicAdd(&cursor[r], 1);
            rows_s[p] = r; cols_s[p] = c;
        }
    }
}

// ---------------- MFMA layer helper (padded linear LDS, no swizzle) ----------------
// element (row,k) at byte row*ROWB + k*2
template<int KS, int ROWB>
__device__ __forceinline__ void gemm_layer(const unsigned short* __restrict__ Bseg,
                                           const char* __restrict__ Xs,
                                           int lane, int cb, f32x4 acc[4])
{
    const bf16x8* bptr = (const bf16x8*)Bseg + (size_t)(cb * KS) * 64 + lane;
#pragma unroll
    for (int ks = 0; ks < KS; ++ks) {
        bf16x8 b = bptr[(size_t)ks * 64];
#pragma unroll
        for (int rb = 0; rb < 4; ++rb) {
            int row = rb * 16 + (lane & 15);
            bf16x8 a = *(const bf16x8*)(Xs + row * ROWB + ks * 64 + ((lane >> 4) << 4));
            acc[rb] = __builtin_amdgcn_mfma_f32_16x16x32_bf16(a, b, acc[rb], 0, 0, 0);
        }
    }
}

// ---------------- H0 precompute (+ fused edge histogram) ----------------
__global__ __launch_bounds__(512, 2)
void h0_kernel(const float* __restrict__ h, const float* __restrict__ eb0,
               const unsigned short* __restrict__ pack,
               const int* __restrict__ eidx, int* __restrict__ cnt,
               unsigned short* __restrict__ H0r, unsigned short* __restrict__ H0c)
{
    __shared__ __align__(16) char Xs[TMN * RB128];
    const int tid = threadIdx.x, lane = tid & 63, cb = tid >> 6;
    const int n0 = blockIdx.x * TMN;

    // fused histogram slice (independent of the GEMM below)
    {
        int e = blockIdx.x * 1024 + tid * 2;
        if (e + 1 < N_EDGES) {
            int2 rr = *(const int2*)(eidx + e);
            atomicAdd(&cnt[rr.x], 1);
            atomicAdd(&cnt[rr.y], 1);
        } else if (e < N_EDGES) {
            atomicAdd(&cnt[eidx[e]], 1);
        }
    }

    {
        const int nl = tid >> 3, sub = tid & 7, n = n0 + nl;
        if (n < N_NODES) {
            const float4* h4 = (const float4*)(h + (size_t)n * HDIM);
#pragma unroll
            for (int q = 0; q < 4; ++q) {
                float4 f = h4[sub + q * 8];
                uint2 u; u.x = f2bf2(f.x, f.y); u.y = f2bf2(f.z, f.w);
                *(uint2*)(Xs + nl * RB128 + (sub + q * 8) * 8) = u;
            }
        } else {
            uint2 z{0, 0};
#pragma unroll
            for (int q = 0; q < 4; ++q)
                *(uint2*)(Xs + nl * RB128 + (sub + q * 8) * 8) = z;
        }
    }
    __syncthreads();

    const int col = cb * 16 + (lane & 15);
    f32x4 acc[4];
    {
        float bias = eb0[col];
#pragma unroll
        for (int rb = 0; rb < 4; ++rb) acc[rb] = f32x4{bias, bias, bias, bias};
        gemm_layer<4, RB128>(pack + OFF_EW0T, Xs, lane, cb, acc);
#pragma unroll
        for (int rb = 0; rb < 4; ++rb)
#pragma unroll
            for (int r = 0; r < 4; ++r) {
                int row = rb * 16 + ((lane >> 4) << 2) + r, n = n0 + row;
                if (n < N_NODES) H0r[(size_t)n * HDIM + col] = f2bf(acc[rb][r]);
            }
    }
    {
#pragma unroll
        for (int rb = 0; rb < 4; ++rb) acc[rb] = f32x4{0.f, 0.f, 0.f, 0.f};
        gemm_layer<4, RB128>(pack + OFF_EW0B, Xs, lane, cb, acc);
#pragma unroll
        for (int rb = 0; rb < 4; ++rb)
#pragma unroll
            for (int r = 0; r < 4; ++r) {
                int row = rb * 16 + ((lane >> 4) << 2) + r, n = n0 + row;
                if (n < N_NODES) H0c[(size_t)n * HDIM + col] = f2bf(acc[rb][r]);
            }
    }
}

// ---------------- edge kernel (sorted order) ----------------
__global__ __launch_bounds__(512, 4)
void egnn_edge_kernel(const unsigned short* __restrict__ H0r,
                      const unsigned short* __restrict__ H0c,
                      const float* __restrict__ pos,
                      const int*   __restrict__ rows_s,
                      const int*   __restrict__ cols_s,
                      const float* __restrict__ w256,
                      const float* __restrict__ eb1, const float* __restrict__ cb0,
                      const float* __restrict__ cW1,
                      const unsigned short* __restrict__ pack,
                      float* __restrict__ m_i,
                      float* __restrict__ pos_upd)
{
    __shared__ __align__(16) char Ya[TME * RB128];   // 17.4KB
    __shared__ __align__(16) char Yb[TME * RB128];   // 17.4KB
    __shared__ float rad_s[TME];
    __shared__ float dif_s[TME][3];
    __shared__ float cu_s[TME][4];
    __shared__ int   rowb_s[TME];

    const int tid = threadIdx.x, lane = tid & 63, cb = tid >> 6;
    const int e0 = blockIdx.x * TME;

    // ---- phase 0: gather H0r[row]+H0c[col], radial term, SiLU -> Ya ----
    {
        const int el = tid >> 3, sub = tid & 7, idx = e0 + el;
        const int r = rows_s[idx];
        const int c = cols_s[idx];
        float dx = pos[(size_t)r * 3 + 0] - pos[(size_t)c * 3 + 0];
        float dy = pos[(size_t)r * 3 + 1] - pos[(size_t)c * 3 + 1];
        float dz = pos[(size_t)r * 3 + 2] - pos[(size_t)c * 3 + 2];
        float rad = dx * dx + dy * dy + dz * dz;
        if (sub == 0) {
            rad_s[el] = rad;
            dif_s[el][0] = dx; dif_s[el][1] = dy; dif_s[el][2] = dz;
            rowb_s[el] = r;
        }
        const bf16x8* ar = (const bf16x8*)(H0r + (size_t)r * HDIM + sub * 16);
        const bf16x8* ac = (const bf16x8*)(H0c + (size_t)c * HDIM + sub * 16);
        bf16x8 a0 = ar[0], a1 = ar[1];
        bf16x8 c0 = ac[0], c1 = ac[1];
        const float4* wp = (const float4*)(w256 + sub * 16);
        float4 w4[4] = { wp[0], wp[1], wp[2], wp[3] };
        const float* wf = (const float*)w4;
        float v[16];
#pragma unroll
        for (int i = 0; i < 8; ++i) v[i]     = bf2f((unsigned short)a0[i]) + bf2f((unsigned short)c0[i]);
#pragma unroll
        for (int i = 0; i < 8; ++i) v[8 + i] = bf2f((unsigned short)a1[i]) + bf2f((unsigned short)c1[i]);
#pragma unroll
        for (int i = 0; i < 16; ++i) v[i] = silu(fmaf(rad, wf[i], v[i]));
#pragma unroll
        for (int c4 = 0; c4 < 4; ++c4) {
            uint2 u;
            u.x = f2bf2(v[c4 * 4 + 0], v[c4 * 4 + 1]);
            u.y = f2bf2(v[c4 * 4 + 2], v[c4 * 4 + 3]);
            *(uint2*)(Ya + el * RB128 + sub * 32 + c4 * 8) = u;
        }
    }
    __syncthreads();

    const int col = cb * 16 + (lane & 15);
    f32x4 acc[4];

    // ---- phase 1: m_ij = silu(Ya @ eW1 + eb1) -> Yb ----
    {
        float bias = eb1[col];
#pragma unroll
        for (int rb = 0; rb < 4; ++rb) acc[rb] = f32x4{bias, bias, bias, bias};
        gemm_layer<4, RB128>(pack + OFF_EW1, Ya, lane, cb, acc);
#pragma unroll
        for (int rb = 0; rb < 4; ++rb)
#pragma unroll
            for (int r = 0; r < 4; ++r) {
                int row = rb * 16 + ((lane >> 4) << 2) + r;
                *(unsigned short*)(Yb + row * RB128 + col * 2) = f2bf(silu(acc[rb][r]));
            }
    }
    __syncthreads();

    // ---- phase 1.5: segment-reduce Yb into m_i (vectorized: 4 cols x 4 rows/thread) ----
    {
        const int cg = tid & 31;       // col group: cols cg*4 .. cg*4+3
        const int sg = tid >> 5;       // 16 chunks of 4 sorted edges
        float r0 = 0.f, r1 = 0.f, r2 = 0.f, r3 = 0.f;
        int cur = rowb_s[sg * 4];
#pragma unroll
        for (int i = 0; i < 4; ++i) {
            int row = sg * 4 + i;
            int rr = rowb_s[row];
            if (rr != cur) {
                float* mp = &m_i[(size_t)cur * HDIM + cg * 4];
                atomicAdd(mp + 0, r0); atomicAdd(mp + 1, r1);
                atomicAdd(mp + 2, r2); atomicAdd(mp + 3, r3);
                r0 = r1 = r2 = r3 = 0.f; cur = rr;
            }
            uint2 u = *(const uint2*)(Yb + row * RB128 + cg * 8);
            r0 += bflo(u.x); r1 += bfhi(u.x);
            r2 += bflo(u.y); r3 += bfhi(u.y);
        }
        float* mp = &m_i[(size_t)cur * HDIM + cg * 4];
        atomicAdd(mp + 0, r0); atomicAdd(mp + 1, r1);
        atomicAdd(mp + 2, r2); atomicAdd(mp + 3, r3);
    }

    // ---- phase 2: coord hidden = silu(Yb @ cW0 + cb0) -> Ya ----
    {
        float bias = cb0[col];
#pragma unroll
        for (int rb = 0; rb < 4; ++rb) acc[rb] = f32x4{bias, bias, bias, bias};
        gemm_layer<4, RB128>(pack + OFF_CW0, Yb, lane, cb, acc);
#pragma unroll
        for (int rb = 0; rb < 4; ++rb)
#pragma unroll
            for (int r = 0; r < 4; ++r) {
                int row = rb * 16 + ((lane >> 4) << 2) + r;
                *(unsigned short*)(Ya + row * RB128 + col * 2) = f2bf(silu(acc[rb][r]));
            }
    }
    __syncthreads();

    // ---- phase 3: coord weight dot; per-edge update into LDS ----
    {
        const int el = tid >> 3, sub = tid & 7;
        float p = 0.f;
#pragma unroll
        for (int i = 0; i < 16; i += 2) {
            int jj = sub * 16 + i;
            unsigned int u = *(const unsigned int*)(Ya + el * RB128 + jj * 2);
            p = fmaf(bflo(u), cW1[jj], p);
            p = fmaf(bfhi(u), cW1[jj + 1], p);
        }
        p += __shfl_down(p, 4, 8);
        p += __shfl_down(p, 2, 8);
        p += __shfl_down(p, 1, 8);
        if (sub == 0) {
            float inv = 1.0f / sqrtf(rad_s[el] + 1e-8f);
            float cwv = p * inv;
            cu_s[el][0] = dif_s[el][0] * cwv;
            cu_s[el][1] = dif_s[el][1] * cwv;
            cu_s[el][2] = dif_s[el][2] * cwv;
        }
    }
    __syncthreads();

    // ---- phase 4: segment-reduce pos updates ----
    if (tid < TME) {
        const int el = tid;
        bool head = (el == 0) || (rowb_s[el] != rowb_s[el - 1]);
        if (head) {
            float sx = 0.f, sy = 0.f, sz = 0.f;
            int r = rowb_s[el];
            int j = el;
            do {
                sx += cu_s[j][0]; sy += cu_s[j][1]; sz += cu_s[j][2];
                ++j;
            } while (j < TME && rowb_s[j] == r);
            atomicAdd(&pos_upd[(size_t)r * 3 + 0], sx);
            atomicAdd(&pos_upd[(size_t)r * 3 + 1], sy);
            atomicAdd(&pos_upd[(size_t)r * 3 + 2], sz);
        }
    }
}

// ---------------- node kernel ----------------
__global__ __launch_bounds__(512)
void egnn_node_kernel(const float* __restrict__ h,
                      const float* __restrict__ pos,
                      const float* __restrict__ m_i,
                      const float* __restrict__ pos_upd,
                      const int*   __restrict__ row_start,
                      const float* __restrict__ nb0, const float* __restrict__ nb1,
                      const unsigned short* __restrict__ pack,
                      float* __restrict__ out_h,
                      float* __restrict__ out_pos)
{
    __shared__ __align__(16) char Xs[TMN * RB256];   // 33.8KB
    __shared__ __align__(16) char Ya[TMN * RB128];   // 17.4KB

    const int tid = threadIdx.x, lane = tid & 63, cb = tid >> 6;
    const int n0 = blockIdx.x * TMN;

    if (tid < TMN * 3) {
        int nl = tid / 3, d = tid % 3;
        int n = n0 + nl;
        if (n < N_NODES) {
            float dv = (float)(row_start[n + 1] - row_start[n]);
            out_pos[(size_t)n * 3 + d] =
                pos[(size_t)n * 3 + d] + pos_upd[(size_t)n * 3 + d] / (dv + 1e-6f);
        }
    }

    {
        const int nl = tid >> 3, sub = tid & 7, n = n0 + nl;
        if (n < N_NODES) {
            const float4* h4 = (const float4*)(h   + (size_t)n * HDIM);
            const float4* m4 = (const float4*)(m_i + (size_t)n * HDIM);
#pragma unroll
            for (int q = 0; q < 4; ++q) {
                float4 fh = h4[sub + q * 8];
                float4 fm = m4[sub + q * 8];
                uint2 uh; uh.x = f2bf2(fh.x, fh.y); uh.y = f2bf2(fh.z, fh.w);
                uint2 um; um.x = f2bf2(fm.x, fm.y); um.y = f2bf2(fm.z, fm.w);
                *(uint2*)(Xs + nl * RB256 + (sub + q * 8) * 8)       = uh;
                *(uint2*)(Xs + nl * RB256 + 256 + (sub + q * 8) * 8) = um;
            }
        } else {
            uint2 z{0, 0};
#pragma unroll
            for (int q = 0; q < 4; ++q) {
                *(uint2*)(Xs + nl * RB256 + (sub + q * 8) * 8)       = z;
                *(uint2*)(Xs + nl * RB256 + 256 + (sub + q * 8) * 8) = z;
            }
        }
    }
    __syncthreads();

    const int col = cb * 16 + (lane & 15);
    f32x4 acc[4];

    {
        float bias = nb0[col];
#pragma unroll
        for (int rb = 0; rb < 4; ++rb) acc[rb] = f32x4{bias, bias, bias, bias};
        gemm_layer<8, RB256>(pack + OFF_NW0, Xs, lane, cb, acc);
#pragma unroll
        for (int rb = 0; rb < 4; ++rb)
#pragma unroll
            for (int r = 0; r < 4; ++r) {
                int row = rb * 16 + ((lane >> 4) << 2) + r;
                *(unsigned short*)(Ya + row * RB128 + col * 2) = f2bf(silu(acc[rb][r]));
            }
    }
    __syncthreads();

    {
        float bias = nb1[col];
#pragma unroll
        for (int rb = 0; rb < 4; ++rb) acc[rb] = f32x4{bias, bias, bias, bias};
        gemm_layer<4, RB128>(pack + OFF_NW1, Ya, lane, cb, acc);
#pragma unroll
        for (int rb = 0; rb < 4; ++rb)
#pragma unroll
            for (int r = 0; r < 4; ++r) {
                int row = rb * 16 + ((lane >> 4) << 2) + r, n = n0 + row;
                if (n < N_NODES)
                    out_h[(size_t)n * HDIM + col] = h[(size_t)n * HDIM + col] + acc[rb][r];
            }
    }
}

extern "C" void kernel_launch(void* const* d_in, const int* in_sizes, int n_in,
                              void* d_out, int out_size, void* d_ws, size_t ws_size,
                              hipStream_t stream) {
    const float* h    = (const float*)d_in[0];
    const float* pos  = (const float*)d_in[1];
    const int*   eidx = (const int*)  d_in[2];
    const float* eW0  = (const float*)d_in[3];
    const float* eb0  = (const float*)d_in[4];
    const float* eW1  = (const float*)d_in[5];
    const float* eb1  = (const float*)d_in[6];
    const float* nW0  = (const float*)d_in[7];
    const float* nb0  = (const float*)d_in[8];
    const float* nW1  = (const float*)d_in[9];
    const float* nb1  = (const float*)d_in[10];
    const float* cW0  = (const float*)d_in[11];
    const float* cb0  = (const float*)d_in[12];
    const float* cW1  = (const float*)d_in[13];

    float* out_h   = (float*)d_out;
    float* out_pos = out_h + (size_t)N_NODES * HDIM;

    // workspace layout
    float* m_i       = (float*)d_ws;                          // N*128 f32  (zeroed)
    float* pos_upd   = m_i + (size_t)N_NODES * HDIM;          // N*3        (zeroed)
    int*   cnt       = (int*)(pos_upd + (size_t)N_NODES * 3); // N          (zeroed)
    int*   row_start = cnt + N_NODES;                         // N+1
    int*   cursor    = row_start + N_NODES + 1;               // N
    int*   rows_s    = cursor + N_NODES;                      // E
    int*   cols_s    = rows_s + N_EDGES;                      // E
    unsigned short* pack = (unsigned short*)(cols_s + N_EDGES);
    unsigned short* H0r  = pack + PACK_ELEMS;                 // N*128 bf16
    unsigned short* H0c  = H0r + (size_t)N_NODES * HDIM;      // N*128 bf16

    size_t zero_bytes = ((size_t)N_NODES * HDIM + (size_t)N_NODES * 3 + N_NODES) * sizeof(float);
    hipMemsetAsync(m_i, 0, zero_bytes, stream);

    pack_weights<<<56, 256, 0, stream>>>(eW0, eW1, cW0, nW0, nW1, pack);

    // h0 GEMM + fused histogram
    h0_kernel<<<(N_NODES + TMN - 1) / TMN, 512, 0, stream>>>(h, eb0, pack, eidx, cnt, H0r, H0c);

    scan_kernel<<<1, 1024, 0, stream>>>(cnt, row_start, cursor);
    scatter_kernel<<<(N_EDGES / 4 + 255) / 256, 256, 0, stream>>>(eidx, cursor, rows_s, cols_s);

    egnn_edge_kernel<<<N_EDGES / TME, 512, 0, stream>>>(
        H0r, H0c, pos, rows_s, cols_s, eW0 + (size_t)256 * HDIM, eb1, cb0, cW1,
        pack, m_i, pos_upd);

    egnn_node_kernel<<<(N_NODES + TMN - 1) / TMN, 512, 0, stream>>>(
        h, pos, m_i, pos_upd, row_start, nb0, nb1, pack, out_h, out_pos);
}

// Round 6
// 355.990 us; speedup vs baseline: 2.1636x; 2.1636x over previous
//
#include <hip/hip_runtime.h>
#include <hip/hip_bf16.h>
#include <cstddef>

#define N_NODES 50000
#define N_EDGES 800000
#define HDIM    128
#define TME     64
#define TMN     64

// padded LDS row strides (bytes)
#define RB128   272
#define RB256   528

// scan geometry
#define SCHUNK  512
#define SNBLK   ((N_NODES + SCHUNK - 1) / SCHUNK)   // 98

typedef __attribute__((ext_vector_type(4))) float f32x4;
typedef __attribute__((ext_vector_type(8))) short bf16x8;

// pack offsets (bf16 elements)
#define OFF_EW0T 0
#define OFF_EW0B 16384
#define OFF_EW1  32768
#define OFF_CW0  49152
#define OFF_NW0  65536
#define OFF_NW1  98304
#define PACK_ELEMS 114688

__device__ __forceinline__ float silu(float x) {
    float e = __expf(-x);
    return __fdividef(x, 1.0f + e);
}
__device__ __forceinline__ unsigned short f2bf(float f) {
    union { __hip_bfloat16 h; unsigned short u; } cv;
    cv.h = __float2bfloat16(f);
    return cv.u;
}
__device__ __forceinline__ unsigned int f2bf2(float a, float b) {
    union { __hip_bfloat162 h; unsigned int u; } cv;
    cv.h = __float22bfloat162_rn(float2{a, b});
    return cv.u;
}
__device__ __forceinline__ float bf2f(unsigned short u) {
    return __uint_as_float(((unsigned int)u) << 16);
}
__device__ __forceinline__ float bflo(unsigned int u) {
    return __uint_as_float(u << 16);
}
__device__ __forceinline__ float bfhi(unsigned int u) {
    return __uint_as_float(u & 0xffff0000u);
}

// ---------------- weight pack ----------------
__global__ void pack_weights(const float* __restrict__ eW0, const float* __restrict__ eW1,
                             const float* __restrict__ cW0, const float* __restrict__ nW0,
                             const float* __restrict__ nW1, unsigned short* __restrict__ pack)
{
    int g = blockIdx.x * blockDim.x + threadIdx.x;   // 0 .. 14335
    int f = g >> 6;
    int lane = g & 63;
    const float* W; int base; int rowoff = 0;
    if (f < 32)       { W = eW0; base = OFF_EW0T; }
    else if (f < 64)  { W = eW0; base = OFF_EW0B; f -= 32; rowoff = 128; }
    else if (f < 96)  { W = eW1; base = OFF_EW1;  f -= 64; }
    else if (f < 128) { W = cW0; base = OFF_CW0;  f -= 96; }
    else if (f < 192) { W = nW0; base = OFF_NW0;  f -= 128; }
    else              { W = nW1; base = OFF_NW1;  f -= 192; }
    int KS = (base == OFF_NW0) ? 8 : 4;
    int cb = f / KS, ks = f % KS;
    int col = cb * 16 + (lane & 15);
    int kbase = rowoff + ks * 32 + ((lane >> 4) << 3);
#pragma unroll
    for (int j = 0; j < 8; ++j)
        pack[(size_t)base + ((size_t)(f * 64 + lane) * 8 + j)] =
            f2bf(W[(size_t)(kbase + j) * HDIM + col]);
}

// ---------------- multi-block scan over cnt[N] ----------------
__global__ __launch_bounds__(256)
void scanA_kernel(const int* __restrict__ cnt, int* __restrict__ bsum) {
    __shared__ int part[256];
    const int b = blockIdx.x, t = threadIdx.x;
    int i0 = b * SCHUNK + t * 2;
    int s = 0;
    if (i0 < N_NODES)     s += cnt[i0];
    if (i0 + 1 < N_NODES) s += cnt[i0 + 1];
    part[t] = s;
    __syncthreads();
    for (int off = 128; off > 0; off >>= 1) {
        if (t < off) part[t] += part[t + off];
        __syncthreads();
    }
    if (t == 0) bsum[b] = part[0];
}

__global__ __launch_bounds__(128)
void scanB_kernel(const int* __restrict__ bsum, int* __restrict__ boff,
                  int* __restrict__ row_start) {
    __shared__ int part[128];
    const int t = threadIdx.x;
    int s = (t < SNBLK) ? bsum[t] : 0;
    part[t] = s;
    __syncthreads();
    for (int off = 1; off < 128; off <<= 1) {
        int tmp = (t >= off) ? part[t - off] : 0;
        __syncthreads();
        part[t] += tmp;
        __syncthreads();
    }
    boff[t] = part[t] - s;           // exclusive
    if (t == 127) row_start[N_NODES] = part[127];
}

__global__ __launch_bounds__(256)
void scanC_kernel(const int* __restrict__ cnt, const int* __restrict__ boff,
                  int* __restrict__ row_start, int* __restrict__ cursor) {
    __shared__ int part[256];
    const int b = blockIdx.x, t = threadIdx.x;
    int i0 = b * SCHUNK + t * 2;
    int c0 = (i0 < N_NODES) ? cnt[i0] : 0;
    int c1 = (i0 + 1 < N_NODES) ? cnt[i0 + 1] : 0;
    int s = c0 + c1;
    part[t] = s;
    __syncthreads();
    for (int off = 1; off < 256; off <<= 1) {
        int tmp = (t >= off) ? part[t - off] : 0;
        __syncthreads();
        part[t] += tmp;
        __syncthreads();
    }
    int base = boff[b] + part[t] - s;
    if (i0 < N_NODES)     { row_start[i0] = base;          cursor[i0] = base; }
    if (i0 + 1 < N_NODES) { row_start[i0 + 1] = base + c0; cursor[i0 + 1] = base + c0; }
}

__global__ void scatter_kernel(const int* __restrict__ eidx, int* __restrict__ cursor,
                               int2* __restrict__ rc) {
    int e = (blockIdx.x * blockDim.x + threadIdx.x) * 4;
    if (e + 3 < N_EDGES) {
        int4 r4 = *(const int4*)(eidx + e);
        int4 c4 = *(const int4*)(eidx + N_EDGES + e);
        int p;
        p = atomicAdd(&cursor[r4.x], 1); rc[p] = int2{r4.x, c4.x};
        p = atomicAdd(&cursor[r4.y], 1); rc[p] = int2{r4.y, c4.y};
        p = atomicAdd(&cursor[r4.z], 1); rc[p] = int2{r4.z, c4.z};
        p = atomicAdd(&cursor[r4.w], 1); rc[p] = int2{r4.w, c4.w};
    } else {
        for (int i = e; i < N_EDGES; ++i) {
            int r = eidx[i], c = eidx[N_EDGES + i];
            int p = atomicAdd(&cursor[r], 1);
            rc[p] = int2{r, c};
        }
    }
}

// ---------------- MFMA layer helper (padded linear LDS) ----------------
template<int KS, int ROWB>
__device__ __forceinline__ void gemm_layer(const unsigned short* __restrict__ Bseg,
                                           const char* __restrict__ Xs,
                                           int lane, int cb, f32x4 acc[4])
{
    const bf16x8* bptr = (const bf16x8*)Bseg + (size_t)(cb * KS) * 64 + lane;
#pragma unroll
    for (int ks = 0; ks < KS; ++ks) {
        bf16x8 b = bptr[(size_t)ks * 64];
#pragma unroll
        for (int rb = 0; rb < 4; ++rb) {
            int row = rb * 16 + (lane & 15);
            bf16x8 a = *(const bf16x8*)(Xs + row * ROWB + ks * 64 + ((lane >> 4) << 4));
            acc[rb] = __builtin_amdgcn_mfma_f32_16x16x32_bf16(a, b, acc[rb], 0, 0, 0);
        }
    }
}

// ---------------- H0 precompute (+ fused edge histogram) ----------------
__global__ __launch_bounds__(512, 2)
void h0_kernel(const float* __restrict__ h, const float* __restrict__ eb0,
               const unsigned short* __restrict__ pack,
               const int* __restrict__ eidx, int* __restrict__ cnt,
               unsigned short* __restrict__ H0r, unsigned short* __restrict__ H0c)
{
    __shared__ __align__(16) char Xs[TMN * RB128];
    const int tid = threadIdx.x, lane = tid & 63, cb = tid >> 6;
    const int n0 = blockIdx.x * TMN;

    {
        int e = blockIdx.x * 1024 + tid * 2;
        if (e + 1 < N_EDGES) {
            int2 rr = *(const int2*)(eidx + e);
            atomicAdd(&cnt[rr.x], 1);
            atomicAdd(&cnt[rr.y], 1);
        } else if (e < N_EDGES) {
            atomicAdd(&cnt[eidx[e]], 1);
        }
    }

    {
        const int nl = tid >> 3, sub = tid & 7, n = n0 + nl;
        if (n < N_NODES) {
            const float4* h4 = (const float4*)(h + (size_t)n * HDIM);
#pragma unroll
            for (int q = 0; q < 4; ++q) {
                float4 f = h4[sub + q * 8];
                uint2 u; u.x = f2bf2(f.x, f.y); u.y = f2bf2(f.z, f.w);
                *(uint2*)(Xs + nl * RB128 + (sub + q * 8) * 8) = u;
            }
        } else {
            uint2 z{0, 0};
#pragma unroll
            for (int q = 0; q < 4; ++q)
                *(uint2*)(Xs + nl * RB128 + (sub + q * 8) * 8) = z;
        }
    }
    __syncthreads();

    const int col = cb * 16 + (lane & 15);
    f32x4 acc[4];
    {
        float bias = eb0[col];
#pragma unroll
        for (int rb = 0; rb < 4; ++rb) acc[rb] = f32x4{bias, bias, bias, bias};
        gemm_layer<4, RB128>(pack + OFF_EW0T, Xs, lane, cb, acc);
#pragma unroll
        for (int rb = 0; rb < 4; ++rb)
#pragma unroll
            for (int r = 0; r < 4; ++r) {
                int row = rb * 16 + ((lane >> 4) << 2) + r, n = n0 + row;
                if (n < N_NODES) H0r[(size_t)n * HDIM + col] = f2bf(acc[rb][r]);
            }
    }
    {
#pragma unroll
        for (int rb = 0; rb < 4; ++rb) acc[rb] = f32x4{0.f, 0.f, 0.f, 0.f};
        gemm_layer<4, RB128>(pack + OFF_EW0B, Xs, lane, cb, acc);
#pragma unroll
        for (int rb = 0; rb < 4; ++rb)
#pragma unroll
            for (int r = 0; r < 4; ++r) {
                int row = rb * 16 + ((lane >> 4) << 2) + r, n = n0 + row;
                if (n < N_NODES) H0c[(size_t)n * HDIM + col] = f2bf(acc[rb][r]);
            }
    }
}

// ---------------- edge kernel (sorted order, XCD-chunked) ----------------
__global__ __launch_bounds__(512, 4)
void egnn_edge_kernel(const unsigned short* __restrict__ H0r,
                      const unsigned short* __restrict__ H0c,
                      const float* __restrict__ pos,
                      const int2*  __restrict__ rc,
                      const float* __restrict__ w256,
                      const float* __restrict__ eb1, const float* __restrict__ cb0,
                      const float* __restrict__ cW1,
                      const unsigned short* __restrict__ pack,
                      float* __restrict__ m_i,
                      float* __restrict__ pos_upd)
{
    __shared__ __align__(16) char Ya[TME * RB128];
    __shared__ __align__(16) char Yb[TME * RB128];
    __shared__ float rad_s[TME];
    __shared__ float dif_s[TME][3];
    __shared__ float cu_s[TME][4];
    __shared__ int   rowb_s[TME];

    const int tid = threadIdx.x, lane = tid & 63, cb = tid >> 6;

    // bijective XCD-chunked block swizzle: adjacent logical blocks share an XCD
    int lb;
    {
        const int nwg = gridDim.x;
        const int q = nwg >> 3, r = nwg & 7;
        const int xcd = blockIdx.x & 7, idx = blockIdx.x >> 3;
        lb = (xcd < r) ? (xcd * (q + 1) + idx) : (r * (q + 1) + (xcd - r) * q + idx);
    }
    const int e0 = lb * TME;

    // ---- phase 0: gather H0r[row]+H0c[col], radial term, SiLU -> Ya ----
    {
        const int el = tid >> 3, sub = tid & 7, idx = e0 + el;
        const int2 rcv = rc[idx];
        const int r = rcv.x, c = rcv.y;
        float dx = pos[(size_t)r * 3 + 0] - pos[(size_t)c * 3 + 0];
        float dy = pos[(size_t)r * 3 + 1] - pos[(size_t)c * 3 + 1];
        float dz = pos[(size_t)r * 3 + 2] - pos[(size_t)c * 3 + 2];
        float rad = dx * dx + dy * dy + dz * dz;
        if (sub == 0) {
            rad_s[el] = rad;
            dif_s[el][0] = dx; dif_s[el][1] = dy; dif_s[el][2] = dz;
            rowb_s[el] = r;
        }
        const bf16x8* ar = (const bf16x8*)(H0r + (size_t)r * HDIM + sub * 16);
        const bf16x8* ac = (const bf16x8*)(H0c + (size_t)c * HDIM + sub * 16);
        bf16x8 a0 = ar[0], a1 = ar[1];
        bf16x8 c0 = ac[0], c1 = ac[1];
        const float4* wp = (const float4*)(w256 + sub * 16);
        float4 w4[4] = { wp[0], wp[1], wp[2], wp[3] };
        const float* wf = (const float*)w4;
        float v[16];
#pragma unroll
        for (int i = 0; i < 8; ++i) v[i]     = bf2f((unsigned short)a0[i]) + bf2f((unsigned short)c0[i]);
#pragma unroll
        for (int i = 0; i < 8; ++i) v[8 + i] = bf2f((unsigned short)a1[i]) + bf2f((unsigned short)c1[i]);
#pragma unroll
        for (int i = 0; i < 16; ++i) v[i] = silu(fmaf(rad, wf[i], v[i]));
#pragma unroll
        for (int c4 = 0; c4 < 4; ++c4) {
            uint2 u;
            u.x = f2bf2(v[c4 * 4 + 0], v[c4 * 4 + 1]);
            u.y = f2bf2(v[c4 * 4 + 2], v[c4 * 4 + 3]);
            *(uint2*)(Ya + el * RB128 + sub * 32 + c4 * 8) = u;
        }
    }
    __syncthreads();

    const int col = cb * 16 + (lane & 15);
    f32x4 acc[4];

    // ---- phase 1: m_ij = silu(Ya @ eW1 + eb1) -> Yb ----
    {
        float bias = eb1[col];
#pragma unroll
        for (int rb = 0; rb < 4; ++rb) acc[rb] = f32x4{bias, bias, bias, bias};
        gemm_layer<4, RB128>(pack + OFF_EW1, Ya, lane, cb, acc);
#pragma unroll
        for (int rb = 0; rb < 4; ++rb)
#pragma unroll
            for (int r = 0; r < 4; ++r) {
                int row = rb * 16 + ((lane >> 4) << 2) + r;
                *(unsigned short*)(Yb + row * RB128 + col * 2) = f2bf(silu(acc[rb][r]));
            }
    }
    __syncthreads();

    // ---- phase 1.5: segment-reduce Yb into m_i (round-4 pattern: 1 col/thread) ----
    {
        const int rcol = tid & 127;
        const int ch   = tid >> 7;            // 4 chunks of 16 sorted edges
        float run = 0.f;
        int cur = rowb_s[ch * 16];
#pragma unroll
        for (int i = 0; i < 16; ++i) {
            int row = ch * 16 + i;
            int rr = rowb_s[row];
            if (rr != cur) {
                atomicAdd(&m_i[(size_t)cur * HDIM + rcol], run);
                run = 0.f; cur = rr;
            }
            unsigned short u = *(const unsigned short*)(Yb + row * RB128 + rcol * 2);
            run += bf2f(u);
        }
        atomicAdd(&m_i[(size_t)cur * HDIM + rcol], run);
    }

    // ---- phase 2: coord hidden = silu(Yb @ cW0 + cb0) -> Ya ----
    {
        float bias = cb0[col];
#pragma unroll
        for (int rb = 0; rb < 4; ++rb) acc[rb] = f32x4{bias, bias, bias, bias};
        gemm_layer<4, RB128>(pack + OFF_CW0, Yb, lane, cb, acc);
#pragma unroll
        for (int rb = 0; rb < 4; ++rb)
#pragma unroll
            for (int r = 0; r < 4; ++r) {
                int row = rb * 16 + ((lane >> 4) << 2) + r;
                *(unsigned short*)(Ya + row * RB128 + col * 2) = f2bf(silu(acc[rb][r]));
            }
    }
    __syncthreads();

    // ---- phase 3: coord weight dot; per-edge update into LDS ----
    {
        const int el = tid >> 3, sub = tid & 7;
        float p = 0.f;
#pragma unroll
        for (int i = 0; i < 16; i += 2) {
            int jj = sub * 16 + i;
            unsigned int u = *(const unsigned int*)(Ya + el * RB128 + jj * 2);
            p = fmaf(bflo(u), cW1[jj], p);
            p = fmaf(bfhi(u), cW1[jj + 1], p);
        }
        p += __shfl_down(p, 4, 8);
        p += __shfl_down(p, 2, 8);
        p += __shfl_down(p, 1, 8);
        if (sub == 0) {
            float inv = 1.0f / sqrtf(rad_s[el] + 1e-8f);
            float cwv = p * inv;
            cu_s[el][0] = dif_s[el][0] * cwv;
            cu_s[el][1] = dif_s[el][1] * cwv;
            cu_s[el][2] = dif_s[el][2] * cwv;
        }
    }
    __syncthreads();

    // ---- phase 4: segment-reduce pos updates ----
    if (tid < TME) {
        const int el = tid;
        bool head = (el == 0) || (rowb_s[el] != rowb_s[el - 1]);
        if (head) {
            float sx = 0.f, sy = 0.f, sz = 0.f;
            int r = rowb_s[el];
            int j = el;
            do {
                sx += cu_s[j][0]; sy += cu_s[j][1]; sz += cu_s[j][2];
                ++j;
            } while (j < TME && rowb_s[j] == r);
            atomicAdd(&pos_upd[(size_t)r * 3 + 0], sx);
            atomicAdd(&pos_upd[(size_t)r * 3 + 1], sy);
            atomicAdd(&pos_upd[(size_t)r * 3 + 2], sz);
        }
    }
}

// ---------------- node kernel ----------------
__global__ __launch_bounds__(512)
void egnn_node_kernel(const float* __restrict__ h,
                      const float* __restrict__ pos,
                      const float* __restrict__ m_i,
                      const float* __restrict__ pos_upd,
                      const int*   __restrict__ row_start,
                      const float* __restrict__ nb0, const float* __restrict__ nb1,
                      const unsigned short* __restrict__ pack,
                      float* __restrict__ out_h,
                      float* __restrict__ out_pos)
{
    __shared__ __align__(16) char Xs[TMN * RB256];
    __shared__ __align__(16) char Ya[TMN * RB128];

    const int tid = threadIdx.x, lane = tid & 63, cb = tid >> 6;
    const int n0 = blockIdx.x * TMN;

    if (tid < TMN * 3) {
        int nl = tid / 3, d = tid % 3;
        int n = n0 + nl;
        if (n < N_NODES) {
            float dv = (float)(row_start[n + 1] - row_start[n]);
            out_pos[(size_t)n * 3 + d] =
                pos[(size_t)n * 3 + d] + pos_upd[(size_t)n * 3 + d] / (dv + 1e-6f);
        }
    }

    {
        const int nl = tid >> 3, sub = tid & 7, n = n0 + nl;
        if (n < N_NODES) {
            const float4* h4 = (const float4*)(h   + (size_t)n * HDIM);
            const float4* m4 = (const float4*)(m_i + (size_t)n * HDIM);
#pragma unroll
            for (int q = 0; q < 4; ++q) {
                float4 fh = h4[sub + q * 8];
                float4 fm = m4[sub + q * 8];
                uint2 uh; uh.x = f2bf2(fh.x, fh.y); uh.y = f2bf2(fh.z, fh.w);
                uint2 um; um.x = f2bf2(fm.x, fm.y); um.y = f2bf2(fm.z, fm.w);
                *(uint2*)(Xs + nl * RB256 + (sub + q * 8) * 8)       = uh;
                *(uint2*)(Xs + nl * RB256 + 256 + (sub + q * 8) * 8) = um;
            }
        } else {
            uint2 z{0, 0};
#pragma unroll
            for (int q = 0; q < 4; ++q) {
                *(uint2*)(Xs + nl * RB256 + (sub + q * 8) * 8)       = z;
                *(uint2*)(Xs + nl * RB256 + 256 + (sub + q * 8) * 8) = z;
            }
        }
    }
    __syncthreads();

    const int col = cb * 16 + (lane & 15);
    f32x4 acc[4];

    {
        float bias = nb0[col];
#pragma unroll
        for (int rb = 0; rb < 4; ++rb) acc[rb] = f32x4{bias, bias, bias, bias};
        gemm_layer<8, RB256>(pack + OFF_NW0, Xs, lane, cb, acc);
#pragma unroll
        for (int rb = 0; rb < 4; ++rb)
#pragma unroll
            for (int r = 0; r < 4; ++r) {
                int row = rb * 16 + ((lane >> 4) << 2) + r;
                *(unsigned short*)(Ya + row * RB128 + col * 2) = f2bf(silu(acc[rb][r]));
            }
    }
    __syncthreads();

    {
        float bias = nb1[col];
#pragma unroll
        for (int rb = 0; rb < 4; ++rb) acc[rb] = f32x4{bias, bias, bias, bias};
        gemm_layer<4, RB128>(pack + OFF_NW1, Ya, lane, cb, acc);
#pragma unroll
        for (int rb = 0; rb < 4; ++rb)
#pragma unroll
            for (int r = 0; r < 4; ++r) {
                int row = rb * 16 + ((lane >> 4) << 2) + r, n = n0 + row;
                if (n < N_NODES)
                    out_h[(size_t)n * HDIM + col] = h[(size_t)n * HDIM + col] + acc[rb][r];
            }
    }
}

extern "C" void kernel_launch(void* const* d_in, const int* in_sizes, int n_in,
                              void* d_out, int out_size, void* d_ws, size_t ws_size,
                              hipStream_t stream) {
    const float* h    = (const float*)d_in[0];
    const float* pos  = (const float*)d_in[1];
    const int*   eidx = (const int*)  d_in[2];
    const float* eW0  = (const float*)d_in[3];
    const float* eb0  = (const float*)d_in[4];
    const float* eW1  = (const float*)d_in[5];
    const float* eb1  = (const float*)d_in[6];
    const float* nW0  = (const float*)d_in[7];
    const float* nb0  = (const float*)d_in[8];
    const float* nW1  = (const float*)d_in[9];
    const float* nb1  = (const float*)d_in[10];
    const float* cW0  = (const float*)d_in[11];
    const float* cb0  = (const float*)d_in[12];
    const float* cW1  = (const float*)d_in[13];

    float* out_h   = (float*)d_out;
    float* out_pos = out_h + (size_t)N_NODES * HDIM;

    // workspace layout
    float* m_i       = (float*)d_ws;                          // N*128 f32  (zeroed)
    float* pos_upd   = m_i + (size_t)N_NODES * HDIM;          // N*3        (zeroed)
    int*   cnt       = (int*)(pos_upd + (size_t)N_NODES * 3); // N          (zeroed)
    int*   row_start = cnt + N_NODES;                         // N+1
    int*   cursor    = row_start + N_NODES + 1;               // N
    int*   bsum      = cursor + N_NODES;                      // 128
    int*   boff      = bsum + 128;                            // 128
    int2*  rc        = (int2*)(boff + 128);                   // E int2
    unsigned short* pack = (unsigned short*)(rc + N_EDGES);
    unsigned short* H0r  = pack + PACK_ELEMS;                 // N*128 bf16
    unsigned short* H0c  = H0r + (size_t)N_NODES * HDIM;      // N*128 bf16

    size_t zero_bytes = ((size_t)N_NODES * HDIM + (size_t)N_NODES * 3 + N_NODES) * sizeof(float);
    hipMemsetAsync(m_i, 0, zero_bytes, stream);

    pack_weights<<<56, 256, 0, stream>>>(eW0, eW1, cW0, nW0, nW1, pack);

    h0_kernel<<<(N_NODES + TMN - 1) / TMN, 512, 0, stream>>>(h, eb0, pack, eidx, cnt, H0r, H0c);

    scanA_kernel<<<SNBLK, 256, 0, stream>>>(cnt, bsum);
    scanB_kernel<<<1, 128, 0, stream>>>(bsum, boff, row_start);
    scanC_kernel<<<SNBLK, 256, 0, stream>>>(cnt, boff, row_start, cursor);
    scatter_kernel<<<(N_EDGES / 4 + 255) / 256, 256, 0, stream>>>(eidx, cursor, rc);

    egnn_edge_kernel<<<N_EDGES / TME, 512, 0, stream>>>(
        H0r, H0c, pos, rc, eW0 + (size_t)256 * HDIM, eb1, cb0, cW1,
        pack, m_i, pos_upd);

    egnn_node_kernel<<<(N_NODES + TMN - 1) / TMN, 512, 0, stream>>>(
        h, pos, m_i, pos_upd, row_start, nb0, nb1, pack, out_h, out_pos);
}

// Round 7
// 338.492 us; speedup vs baseline: 2.2754x; 1.0517x over previous
//
#include <hip/hip_runtime.h>
#include <hip/hip_bf16.h>
#include <cstddef>

#define N_NODES 50000
#define N_EDGES 800000
#define HDIM    128
#define TME     64
#define TMN     64

// padded LDS row strides (bytes)
#define RB128   272
#define RB256   528

// scan geometry
#define SCHUNK  512
#define SNBLK   ((N_NODES + SCHUNK - 1) / SCHUNK)   // 98

typedef __attribute__((ext_vector_type(4))) float f32x4;
typedef __attribute__((ext_vector_type(8))) short bf16x8;

// pack offsets (bf16 elements)
#define OFF_EW0T 0
#define OFF_EW0B 16384
#define OFF_EW1  32768
#define OFF_CW0  49152
#define OFF_NW0  65536
#define OFF_NW1  98304
#define PACK_ELEMS 114688

__device__ __forceinline__ float silu(float x) {
    float e = __expf(-x);
    return __fdividef(x, 1.0f + e);
}
__device__ __forceinline__ unsigned short f2bf(float f) {
    union { __hip_bfloat16 h; unsigned short u; } cv;
    cv.h = __float2bfloat16(f);
    return cv.u;
}
__device__ __forceinline__ unsigned int f2bf2(float a, float b) {
    union { __hip_bfloat162 h; unsigned int u; } cv;
    cv.h = __float22bfloat162_rn(float2{a, b});
    return cv.u;
}
__device__ __forceinline__ float bf2f(unsigned short u) {
    return __uint_as_float(((unsigned int)u) << 16);
}
__device__ __forceinline__ float bflo(unsigned int u) {
    return __uint_as_float(u << 16);
}
__device__ __forceinline__ float bfhi(unsigned int u) {
    return __uint_as_float(u & 0xffff0000u);
}

// ---------------- weight pack (layout unchanged: same mapping serves as
// B-frag of W or A-frag of W^T) ----------------
__global__ void pack_weights(const float* __restrict__ eW0, const float* __restrict__ eW1,
                             const float* __restrict__ cW0, const float* __restrict__ nW0,
                             const float* __restrict__ nW1, unsigned short* __restrict__ pack)
{
    int g = blockIdx.x * blockDim.x + threadIdx.x;   // 0 .. 14335
    int f = g >> 6;
    int lane = g & 63;
    const float* W; int base; int rowoff = 0;
    if (f < 32)       { W = eW0; base = OFF_EW0T; }
    else if (f < 64)  { W = eW0; base = OFF_EW0B; f -= 32; rowoff = 128; }
    else if (f < 96)  { W = eW1; base = OFF_EW1;  f -= 64; }
    else if (f < 128) { W = cW0; base = OFF_CW0;  f -= 96; }
    else if (f < 192) { W = nW0; base = OFF_NW0;  f -= 128; }
    else              { W = nW1; base = OFF_NW1;  f -= 192; }
    int KS = (base == OFF_NW0) ? 8 : 4;
    int cb = f / KS, ks = f % KS;
    int col = cb * 16 + (lane & 15);
    int kbase = rowoff + ks * 32 + ((lane >> 4) << 3);
#pragma unroll
    for (int j = 0; j < 8; ++j)
        pack[(size_t)base + ((size_t)(f * 64 + lane) * 8 + j)] =
            f2bf(W[(size_t)(kbase + j) * HDIM + col]);
}

// ---------------- multi-block scan over cnt[N] ----------------
__global__ __launch_bounds__(256)
void scanA_kernel(const int* __restrict__ cnt, int* __restrict__ bsum) {
    __shared__ int part[256];
    const int b = blockIdx.x, t = threadIdx.x;
    int i0 = b * SCHUNK + t * 2;
    int s = 0;
    if (i0 < N_NODES)     s += cnt[i0];
    if (i0 + 1 < N_NODES) s += cnt[i0 + 1];
    part[t] = s;
    __syncthreads();
    for (int off = 128; off > 0; off >>= 1) {
        if (t < off) part[t] += part[t + off];
        __syncthreads();
    }
    if (t == 0) bsum[b] = part[0];
}

__global__ __launch_bounds__(128)
void scanB_kernel(const int* __restrict__ bsum, int* __restrict__ boff,
                  int* __restrict__ row_start) {
    __shared__ int part[128];
    const int t = threadIdx.x;
    int s = (t < SNBLK) ? bsum[t] : 0;
    part[t] = s;
    __syncthreads();
    for (int off = 1; off < 128; off <<= 1) {
        int tmp = (t >= off) ? part[t - off] : 0;
        __syncthreads();
        part[t] += tmp;
        __syncthreads();
    }
    boff[t] = part[t] - s;           // exclusive
    if (t == 127) row_start[N_NODES] = part[127];
}

__global__ __launch_bounds__(256)
void scanC_kernel(const int* __restrict__ cnt, const int* __restrict__ boff,
                  int* __restrict__ row_start, int* __restrict__ cursor) {
    __shared__ int part[256];
    const int b = blockIdx.x, t = threadIdx.x;
    int i0 = b * SCHUNK + t * 2;
    int c0 = (i0 < N_NODES) ? cnt[i0] : 0;
    int c1 = (i0 + 1 < N_NODES) ? cnt[i0 + 1] : 0;
    int s = c0 + c1;
    part[t] = s;
    __syncthreads();
    for (int off = 1; off < 256; off <<= 1) {
        int tmp = (t >= off) ? part[t - off] : 0;
        __syncthreads();
        part[t] += tmp;
        __syncthreads();
    }
    int base = boff[b] + part[t] - s;
    if (i0 < N_NODES)     { row_start[i0] = base;          cursor[i0] = base; }
    if (i0 + 1 < N_NODES) { row_start[i0 + 1] = base + c0; cursor[i0 + 1] = base + c0; }
}

__global__ void scatter_kernel(const int* __restrict__ eidx, int* __restrict__ cursor,
                               int2* __restrict__ rc) {
    int e = (blockIdx.x * blockDim.x + threadIdx.x) * 4;
    if (e + 3 < N_EDGES) {
        int4 r4 = *(const int4*)(eidx + e);
        int4 c4 = *(const int4*)(eidx + N_EDGES + e);
        int p;
        p = atomicAdd(&cursor[r4.x], 1); rc[p] = int2{r4.x, c4.x};
        p = atomicAdd(&cursor[r4.y], 1); rc[p] = int2{r4.y, c4.y};
        p = atomicAdd(&cursor[r4.z], 1); rc[p] = int2{r4.z, c4.z};
        p = atomicAdd(&cursor[r4.w], 1); rc[p] = int2{r4.w, c4.w};
    } else {
        for (int i = e; i < N_EDGES; ++i) {
            int r = eidx[i], c = eidx[N_EDGES + i];
            int p = atomicAdd(&cursor[r], 1);
            rc[p] = int2{r, c};
        }
    }
}

// ---------------- swapped-operand MFMA layer ----------------
// Computes Out^T = W^T @ X^T: A = packed weights (same layout as before),
// B = activation tile rows read as k-vectors (identical LDS addressing).
// acc[eb][r] = Out[row = eb*16 + (lane&15)][feat j = cb*16 + (lane>>4)*4 + r]
template<int KS, int ROWB>
__device__ __forceinline__ void gemm_layer_T(const unsigned short* __restrict__ Wseg,
                                             const char* __restrict__ Xs,
                                             int lane, int cb, f32x4 acc[4])
{
    const bf16x8* aptr = (const bf16x8*)Wseg + (size_t)(cb * KS) * 64 + lane;
#pragma unroll
    for (int ks = 0; ks < KS; ++ks) {
        bf16x8 a = aptr[(size_t)ks * 64];
#pragma unroll
        for (int eb = 0; eb < 4; ++eb) {
            int row = eb * 16 + (lane & 15);
            bf16x8 b = *(const bf16x8*)(Xs + row * ROWB + ks * 64 + ((lane >> 4) << 4));
            acc[eb] = __builtin_amdgcn_mfma_f32_16x16x32_bf16(a, b, acc[eb], 0, 0, 0);
        }
    }
}

// ---------------- H0 precompute (+ fused edge histogram) ----------------
__global__ __launch_bounds__(512, 2)
void h0_kernel(const float* __restrict__ h, const float* __restrict__ eb0,
               const unsigned short* __restrict__ pack,
               const int* __restrict__ eidx, int* __restrict__ cnt,
               unsigned short* __restrict__ H0r, unsigned short* __restrict__ H0c)
{
    __shared__ __align__(16) char Xs[TMN * RB128];
    const int tid = threadIdx.x, lane = tid & 63, cb = tid >> 6;
    const int n0 = blockIdx.x * TMN;

    {
        int e = blockIdx.x * 1024 + tid * 2;
        if (e + 1 < N_EDGES) {
            int2 rr = *(const int2*)(eidx + e);
            atomicAdd(&cnt[rr.x], 1);
            atomicAdd(&cnt[rr.y], 1);
        } else if (e < N_EDGES) {
            atomicAdd(&cnt[eidx[e]], 1);
        }
    }

    {
        const int nl = tid >> 3, sub = tid & 7, n = n0 + nl;
        if (n < N_NODES) {
            const float4* h4 = (const float4*)(h + (size_t)n * HDIM);
#pragma unroll
            for (int q = 0; q < 4; ++q) {
                float4 f = h4[sub + q * 8];
                uint2 u; u.x = f2bf2(f.x, f.y); u.y = f2bf2(f.z, f.w);
                *(uint2*)(Xs + nl * RB128 + (sub + q * 8) * 8) = u;
            }
        } else {
            uint2 z{0, 0};
#pragma unroll
            for (int q = 0; q < 4; ++q)
                *(uint2*)(Xs + nl * RB128 + (sub + q * 8) * 8) = z;
        }
    }
    __syncthreads();

    const int j0 = cb * 16 + ((lane >> 4) << 2);
    f32x4 acc[4];
    {
        float4 b0 = *(const float4*)(eb0 + j0);
#pragma unroll
        for (int eb = 0; eb < 4; ++eb) acc[eb] = f32x4{b0.x, b0.y, b0.z, b0.w};
        gemm_layer_T<4, RB128>(pack + OFF_EW0T, Xs, lane, cb, acc);
#pragma unroll
        for (int eb = 0; eb < 4; ++eb) {
            int n = n0 + eb * 16 + (lane & 15);
            if (n < N_NODES) {
                uint2 u; u.x = f2bf2(acc[eb][0], acc[eb][1]); u.y = f2bf2(acc[eb][2], acc[eb][3]);
                *(uint2*)(H0r + (size_t)n * HDIM + j0) = u;
            }
        }
    }
    {
#pragma unroll
        for (int eb = 0; eb < 4; ++eb) acc[eb] = f32x4{0.f, 0.f, 0.f, 0.f};
        gemm_layer_T<4, RB128>(pack + OFF_EW0B, Xs, lane, cb, acc);
#pragma unroll
        for (int eb = 0; eb < 4; ++eb) {
            int n = n0 + eb * 16 + (lane & 15);
            if (n < N_NODES) {
                uint2 u; u.x = f2bf2(acc[eb][0], acc[eb][1]); u.y = f2bf2(acc[eb][2], acc[eb][3]);
                *(uint2*)(H0c + (size_t)n * HDIM + j0) = u;
            }
        }
    }
}

// ---------------- edge kernel (sorted order, XCD-chunked) ----------------
__global__ __launch_bounds__(512, 4)
void egnn_edge_kernel(const unsigned short* __restrict__ H0r,
                      const unsigned short* __restrict__ H0c,
                      const float* __restrict__ pos,
                      const int2*  __restrict__ rc,
                      const float* __restrict__ w256,
                      const float* __restrict__ eb1, const float* __restrict__ cb0,
                      const float* __restrict__ cW1,
                      const unsigned short* __restrict__ pack,
                      float* __restrict__ m_i,
                      float* __restrict__ pos_upd)
{
    __shared__ __align__(16) char Ya[TME * RB128];
    __shared__ __align__(16) char Yb[TME * RB128];
    __shared__ float pw[8][TME];
    __shared__ float rad_s[TME];
    __shared__ float dif_s[TME][3];
    __shared__ float cu_s[TME][4];
    __shared__ int   rowb_s[TME];

    const int tid = threadIdx.x, lane = tid & 63, cb = tid >> 6;

    // bijective XCD-chunked block swizzle
    int lb;
    {
        const int nwg = gridDim.x;
        const int q = nwg >> 3, r = nwg & 7;
        const int xcd = blockIdx.x & 7, idx = blockIdx.x >> 3;
        lb = (xcd < r) ? (xcd * (q + 1) + idx) : (r * (q + 1) + (xcd - r) * q + idx);
    }
    const int e0 = lb * TME;

    // ---- phase 0: gather H0r[row]+H0c[col], radial term, SiLU -> Ya ----
    {
        const int el = tid >> 3, sub = tid & 7, idx = e0 + el;
        const int2 rcv = rc[idx];
        const int r = rcv.x, c = rcv.y;
        float dx = pos[(size_t)r * 3 + 0] - pos[(size_t)c * 3 + 0];
        float dy = pos[(size_t)r * 3 + 1] - pos[(size_t)c * 3 + 1];
        float dz = pos[(size_t)r * 3 + 2] - pos[(size_t)c * 3 + 2];
        float rad = dx * dx + dy * dy + dz * dz;
        if (sub == 0) {
            rad_s[el] = rad;
            dif_s[el][0] = dx; dif_s[el][1] = dy; dif_s[el][2] = dz;
            rowb_s[el] = r;
        }
        const bf16x8* ar = (const bf16x8*)(H0r + (size_t)r * HDIM + sub * 16);
        const bf16x8* ac = (const bf16x8*)(H0c + (size_t)c * HDIM + sub * 16);
        bf16x8 a0 = ar[0], a1 = ar[1];
        bf16x8 c0 = ac[0], c1 = ac[1];
        const float4* wp = (const float4*)(w256 + sub * 16);
        float4 w4[4] = { wp[0], wp[1], wp[2], wp[3] };
        const float* wf = (const float*)w4;
        float v[16];
#pragma unroll
        for (int i = 0; i < 8; ++i) v[i]     = bf2f((unsigned short)a0[i]) + bf2f((unsigned short)c0[i]);
#pragma unroll
        for (int i = 0; i < 8; ++i) v[8 + i] = bf2f((unsigned short)a1[i]) + bf2f((unsigned short)c1[i]);
#pragma unroll
        for (int i = 0; i < 16; ++i) v[i] = silu(fmaf(rad, wf[i], v[i]));
#pragma unroll
        for (int c4 = 0; c4 < 4; ++c4) {
            uint2 u;
            u.x = f2bf2(v[c4 * 4 + 0], v[c4 * 4 + 1]);
            u.y = f2bf2(v[c4 * 4 + 2], v[c4 * 4 + 3]);
            *(uint2*)(Ya + el * RB128 + sub * 32 + c4 * 8) = u;
        }
    }
    __syncthreads();

    const int j0 = cb * 16 + ((lane >> 4) << 2);
    f32x4 acc[4];

    // ---- phase 1: m_ij = silu(Ya @ eW1 + eb1) -> Yb (vectorized b64 writes) ----
    {
        float4 b1 = *(const float4*)(eb1 + j0);
#pragma unroll
        for (int eb = 0; eb < 4; ++eb) acc[eb] = f32x4{b1.x, b1.y, b1.z, b1.w};
        gemm_layer_T<4, RB128>(pack + OFF_EW1, Ya, lane, cb, acc);
#pragma unroll
        for (int eb = 0; eb < 4; ++eb) {
            int e = eb * 16 + (lane & 15);
            float s0 = silu(acc[eb][0]), s1 = silu(acc[eb][1]);
            float s2 = silu(acc[eb][2]), s3 = silu(acc[eb][3]);
            uint2 u; u.x = f2bf2(s0, s1); u.y = f2bf2(s2, s3);
            *(uint2*)(Yb + e * RB128 + j0 * 2) = u;
        }
    }
    __syncthreads();

    // ---- phase 1.5: segment-reduce Yb into m_i (1 col/thread, 16-edge chunks) ----
    {
        const int rcol = tid & 127;
        const int ch   = tid >> 7;
        float run = 0.f;
        int cur = rowb_s[ch * 16];
#pragma unroll
        for (int i = 0; i < 16; ++i) {
            int row = ch * 16 + i;
            int rr = rowb_s[row];
            if (rr != cur) {
                atomicAdd(&m_i[(size_t)cur * HDIM + rcol], run);
                run = 0.f; cur = rr;
            }
            unsigned short u = *(const unsigned short*)(Yb + row * RB128 + rcol * 2);
            run += bf2f(u);
        }
        atomicAdd(&m_i[(size_t)cur * HDIM + rcol], run);
    }

    // ---- phase 2+3 fused: coord hidden in regs, dot with cW1, cross-wave reduce ----
    {
        float4 b2 = *(const float4*)(cb0 + j0);
#pragma unroll
        for (int eb = 0; eb < 4; ++eb) acc[eb] = f32x4{b2.x, b2.y, b2.z, b2.w};
        gemm_layer_T<4, RB128>(pack + OFF_CW0, Yb, lane, cb, acc);
        float4 w1 = *(const float4*)(cW1 + j0);
        float pe[4];
#pragma unroll
        for (int eb = 0; eb < 4; ++eb) {
            float p;
            p = silu(acc[eb][0]) * w1.x;
            p = fmaf(silu(acc[eb][1]), w1.y, p);
            p = fmaf(silu(acc[eb][2]), w1.z, p);
            p = fmaf(silu(acc[eb][3]), w1.w, p);
            p += __shfl_xor(p, 16);
            p += __shfl_xor(p, 32);
            pe[eb] = p;
        }
        if (lane < 16) {
#pragma unroll
            for (int eb = 0; eb < 4; ++eb) pw[cb][eb * 16 + lane] = pe[eb];
        }
    }
    __syncthreads();

    if (tid < TME) {
        float s = 0.f;
#pragma unroll
        for (int w = 0; w < 8; ++w) s += pw[w][tid];
        float inv = 1.0f / sqrtf(rad_s[tid] + 1e-8f);
        float cwv = s * inv;
        cu_s[tid][0] = dif_s[tid][0] * cwv;
        cu_s[tid][1] = dif_s[tid][1] * cwv;
        cu_s[tid][2] = dif_s[tid][2] * cwv;
    }
    __syncthreads();

    // ---- phase 4: segment-reduce pos updates ----
    if (tid < TME) {
        const int el = tid;
        bool head = (el == 0) || (rowb_s[el] != rowb_s[el - 1]);
        if (head) {
            float sx = 0.f, sy = 0.f, sz = 0.f;
            int r = rowb_s[el];
            int j = el;
            do {
                sx += cu_s[j][0]; sy += cu_s[j][1]; sz += cu_s[j][2];
                ++j;
            } while (j < TME && rowb_s[j] == r);
            atomicAdd(&pos_upd[(size_t)r * 3 + 0], sx);
            atomicAdd(&pos_upd[(size_t)r * 3 + 1], sy);
            atomicAdd(&pos_upd[(size_t)r * 3 + 2], sz);
        }
    }
}

// ---------------- node kernel ----------------
__global__ __launch_bounds__(512)
void egnn_node_kernel(const float* __restrict__ h,
                      const float* __restrict__ pos,
                      const float* __restrict__ m_i,
                      const float* __restrict__ pos_upd,
                      const int*   __restrict__ row_start,
                      const float* __restrict__ nb0, const float* __restrict__ nb1,
                      const unsigned short* __restrict__ pack,
                      float* __restrict__ out_h,
                      float* __restrict__ out_pos)
{
    __shared__ __align__(16) char Xs[TMN * RB256];
    __shared__ __align__(16) char Ya[TMN * RB128];

    const int tid = threadIdx.x, lane = tid & 63, cb = tid >> 6;
    const int n0 = blockIdx.x * TMN;

    if (tid < TMN * 3) {
        int nl = tid / 3, d = tid % 3;
        int n = n0 + nl;
        if (n < N_NODES) {
            float dv = (float)(row_start[n + 1] - row_start[n]);
            out_pos[(size_t)n * 3 + d] =
                pos[(size_t)n * 3 + d] + pos_upd[(size_t)n * 3 + d] / (dv + 1e-6f);
        }
    }

    {
        const int nl = tid >> 3, sub = tid & 7, n = n0 + nl;
        if (n < N_NODES) {
            const float4* h4 = (const float4*)(h   + (size_t)n * HDIM);
            const float4* m4 = (const float4*)(m_i + (size_t)n * HDIM);
#pragma unroll
            for (int q = 0; q < 4; ++q) {
                float4 fh = h4[sub + q * 8];
                float4 fm = m4[sub + q * 8];
                uint2 uh; uh.x = f2bf2(fh.x, fh.y); uh.y = f2bf2(fh.z, fh.w);
                uint2 um; um.x = f2bf2(fm.x, fm.y); um.y = f2bf2(fm.z, fm.w);
                *(uint2*)(Xs + nl * RB256 + (sub + q * 8) * 8)       = uh;
                *(uint2*)(Xs + nl * RB256 + 256 + (sub + q * 8) * 8) = um;
            }
        } else {
            uint2 z{0, 0};
#pragma unroll
            for (int q = 0; q < 4; ++q) {
                *(uint2*)(Xs + nl * RB256 + (sub + q * 8) * 8)       = z;
                *(uint2*)(Xs + nl * RB256 + 256 + (sub + q * 8) * 8) = z;
            }
        }
    }
    __syncthreads();

    const int j0 = cb * 16 + ((lane >> 4) << 2);
    f32x4 acc[4];

    {
        float4 b0 = *(const float4*)(nb0 + j0);
#pragma unroll
        for (int eb = 0; eb < 4; ++eb) acc[eb] = f32x4{b0.x, b0.y, b0.z, b0.w};
        gemm_layer_T<8, RB256>(pack + OFF_NW0, Xs, lane, cb, acc);
#pragma unroll
        for (int eb = 0; eb < 4; ++eb) {
            int nl = eb * 16 + (lane & 15);
            float s0 = silu(acc[eb][0]), s1 = silu(acc[eb][1]);
            float s2 = silu(acc[eb][2]), s3 = silu(acc[eb][3]);
            uint2 u; u.x = f2bf2(s0, s1); u.y = f2bf2(s2, s3);
            *(uint2*)(Ya + nl * RB128 + j0 * 2) = u;
        }
    }
    __syncthreads();

    {
        float4 b1 = *(const float4*)(nb1 + j0);
#pragma unroll
        for (int eb = 0; eb < 4; ++eb) acc[eb] = f32x4{b1.x, b1.y, b1.z, b1.w};
        gemm_layer_T<4, RB128>(pack + OFF_NW1, Ya, lane, cb, acc);
#pragma unroll
        for (int eb = 0; eb < 4; ++eb) {
            int n = n0 + eb * 16 + (lane & 15);
            if (n < N_NODES) {
                float4 hv = *(const float4*)(h + (size_t)n * HDIM + j0);
                float4 o;
                o.x = hv.x + acc[eb][0]; o.y = hv.y + acc[eb][1];
                o.z = hv.z + acc[eb][2]; o.w = hv.w + acc[eb][3];
                *(float4*)(out_h + (size_t)n * HDIM + j0) = o;
            }
        }
    }
}

extern "C" void kernel_launch(void* const* d_in, const int* in_sizes, int n_in,
                              void* d_out, int out_size, void* d_ws, size_t ws_size,
                              hipStream_t stream) {
    const float* h    = (const float*)d_in[0];
    const float* pos  = (const float*)d_in[1];
    const int*   eidx = (const int*)  d_in[2];
    const float* eW0  = (const float*)d_in[3];
    const float* eb0  = (const float*)d_in[4];
    const float* eW1  = (const float*)d_in[5];
    const float* eb1  = (const float*)d_in[6];
    const float* nW0  = (const float*)d_in[7];
    const float* nb0  = (const float*)d_in[8];
    const float* nW1  = (const float*)d_in[9];
    const float* nb1  = (const float*)d_in[10];
    const float* cW0  = (const float*)d_in[11];
    const float* cb0  = (const float*)d_in[12];
    const float* cW1  = (const float*)d_in[13];

    float* out_h   = (float*)d_out;
    float* out_pos = out_h + (size_t)N_NODES * HDIM;

    // workspace layout
    float* m_i       = (float*)d_ws;                          // N*128 f32  (zeroed)
    float* pos_upd   = m_i + (size_t)N_NODES * HDIM;          // N*3        (zeroed)
    int*   cnt       = (int*)(pos_upd + (size_t)N_NODES * 3); // N          (zeroed)
    int*   row_start = cnt + N_NODES;                         // N+1
    int*   cursor    = row_start + N_NODES + 1;               // N
    int*   bsum      = cursor + N_NODES;                      // 128
    int*   boff      = bsum + 128;                            // 128
    int2*  rc        = (int2*)(boff + 128);                   // E int2
    unsigned short* pack = (unsigned short*)(rc + N_EDGES);
    unsigned short* H0r  = pack + PACK_ELEMS;                 // N*128 bf16
    unsigned short* H0c  = H0r + (size_t)N_NODES * HDIM;      // N*128 bf16

    size_t zero_bytes = ((size_t)N_NODES * HDIM + (size_t)N_NODES * 3 + N_NODES) * sizeof(float);
    hipMemsetAsync(m_i, 0, zero_bytes, stream);

    pack_weights<<<56, 256, 0, stream>>>(eW0, eW1, cW0, nW0, nW1, pack);

    h0_kernel<<<(N_NODES + TMN - 1) / TMN, 512, 0, stream>>>(h, eb0, pack, eidx, cnt, H0r, H0c);

    scanA_kernel<<<SNBLK, 256, 0, stream>>>(cnt, bsum);
    scanB_kernel<<<1, 128, 0, stream>>>(bsum, boff, row_start);
    scanC_kernel<<<SNBLK, 256, 0, stream>>>(cnt, boff, row_start, cursor);
    scatter_kernel<<<(N_EDGES / 4 + 255) / 256, 256, 0, stream>>>(eidx, cursor, rc);

    egnn_edge_kernel<<<N_EDGES / TME, 512, 0, stream>>>(
        H0r, H0c, pos, rc, eW0 + (size_t)256 * HDIM, eb1, cb0, cW1,
        pack, m_i, pos_upd);

    egnn_node_kernel<<<(N_NODES + TMN - 1) / TMN, 512, 0, stream>>>(
        h, pos, m_i, pos_upd, row_start, nb0, nb1, pack, out_h, out_pos);
}